// Round 4
// baseline (1640.341 us; speedup 1.0000x reference)
//
#include <hip/hip_runtime.h>
#include <hip/hip_fp16.h>

#define N_IN 200000
#define N_OUT 200000
#define K_VOL 27
#define M_PAIRS 100000
#define C_IN 64
#define C_OUT 64
#define NPAIRS (K_VOL * M_PAIRS)     // 2,700,000

#define NTILES (N_OUT / 64)          // 3125 output tiles of 64 rows
#define NBUCKETS (NTILES * K_VOL)    // 84,375
#define SCAN_NB1 330                 // ceil((NBUCKETS+1)/256)

#define LDS_PAD 72                   // ushort row stride for Asm/Wsm (144B)
#define OT_PAD 68                    // float row stride for out_tile (272B, 16B-aligned)

typedef __attribute__((ext_vector_type(4))) float floatx4;
typedef __attribute__((ext_vector_type(8))) short shortx8;
typedef __attribute__((ext_vector_type(8))) _Float16 halfx8;

// ---- workspace layout (bytes) ----
#define FEATS_OFF   0UL
#define FEATS_BYTES (200000UL * 64 * 2)              // 25,600,000 (f16)
#define WT_OFF      (FEATS_OFF + FEATS_BYTES)
#define WT_BYTES    (27UL * 64 * 64 * 2)             // 221,184 (f16, [k][o][c])
#define OFFS_OFF    ((WT_OFF + WT_BYTES + 255UL) & ~255UL)
#define OFFS_BYTES  (337920UL)                       // (NBUCKETS+1) ints, padded
#define CNT_OFF     (OFFS_OFF + OFFS_BYTES)          // counts, reused as cursor
#define CNT_BYTES   (337920UL)
#define BSUM_OFF    (CNT_OFF + CNT_BYTES)
#define BSUM_BYTES  (2048UL)
#define SORT_OFF    (BSUM_OFF + BSUM_BYTES)
#define SORT_BYTES  (2700000UL * 4)                  // 10,800,000
#define WS_NEEDED   (SORT_OFF + SORT_BYTES)          // ~37.3 MB (< proven 51.4 MB)

static __device__ __forceinline__ ushort f32_to_f16_bits(float f) {
    union { _Float16 h; ushort u; } cv;
    cv.h = (_Float16)f;
    return cv.u;
}

// ---------------- prep ----------------
__global__ void cvt_feats_kernel(const float* __restrict__ src, ushort* __restrict__ dst, int n4) {
    int i = blockIdx.x * blockDim.x + threadIdx.x;
    if (i >= n4) return;
    float4 v = ((const float4*)src)[i];
    ushort4 o;
    o.x = f32_to_f16_bits(v.x); o.y = f32_to_f16_bits(v.y);
    o.z = f32_to_f16_bits(v.z); o.w = f32_to_f16_bits(v.w);
    ((ushort4*)dst)[i] = o;
}

// kernel[k][c][o] fp32 -> wt[k][o][c] f16
__global__ void cvt_wt_kernel(const float* __restrict__ w, ushort* __restrict__ wt) {
    int idx = blockIdx.x * blockDim.x + threadIdx.x;
    if (idx >= K_VOL * C_IN * C_OUT) return;
    int k   = idx >> 12;
    int rem = idx & 4095;
    int c   = rem >> 6;
    int o   = rem & 63;
    wt[(k << 12) + (o << 6) + c] = f32_to_f16_bits(w[idx]);
}

// ---------------- counting sort by bucket = (o>>6)*27 + k ----------------
__global__ void hist_kernel(const int* __restrict__ omap, int* __restrict__ counts) {
    int p = blockIdx.x * blockDim.x + threadIdx.x;
    if (p >= NPAIRS) return;
    int k = p / M_PAIRS;
    int o = omap[p];
    atomicAdd(&counts[(o >> 6) * K_VOL + k], 1);
}

__global__ void scan1_kernel(const int* __restrict__ counts, int* __restrict__ bsum) {
    __shared__ int sd[256];
    int tid = threadIdx.x;
    int i = blockIdx.x * 256 + tid;
    sd[tid] = (i < NBUCKETS) ? counts[i] : 0;
    __syncthreads();
    for (int s = 128; s > 0; s >>= 1) {
        if (tid < s) sd[tid] += sd[tid + s];
        __syncthreads();
    }
    if (tid == 0) bsum[blockIdx.x] = sd[0];
}

__global__ void scan2_kernel(int* __restrict__ bsum) {
    __shared__ int sd[512];
    int tid = threadIdx.x;
    int v = (tid < SCAN_NB1) ? bsum[tid] : 0;
    sd[tid] = v;
    __syncthreads();
    for (int off = 1; off < 512; off <<= 1) {
        int t = (tid >= off) ? sd[tid - off] : 0;
        __syncthreads();
        sd[tid] += t;
        __syncthreads();
    }
    if (tid < SCAN_NB1) bsum[tid] = sd[tid] - v;  // exclusive
}

__global__ void scan3_kernel(int* __restrict__ counts_cursor, const int* __restrict__ bsum,
                             int* __restrict__ offsets) {
    __shared__ int sd[256];
    int tid = threadIdx.x;
    int i = blockIdx.x * 256 + tid;
    int v = (i < NBUCKETS) ? counts_cursor[i] : 0;
    sd[tid] = v;
    __syncthreads();
    for (int off = 1; off < 256; off <<= 1) {
        int t = (tid >= off) ? sd[tid - off] : 0;
        __syncthreads();
        sd[tid] += t;
        __syncthreads();
    }
    int excl = sd[tid] - v + bsum[blockIdx.x];
    if (i <= NBUCKETS) offsets[i] = excl;
    if (i < NBUCKETS) counts_cursor[i] = excl;
}

// sorted record: in_row (18b) | o_local (6b) << 18
__global__ void fill_kernel(const int* __restrict__ imap, const int* __restrict__ omap,
                            int* __restrict__ cursor, int* __restrict__ sorted_arr) {
    int p = blockIdx.x * blockDim.x + threadIdx.x;
    if (p >= NPAIRS) return;
    int k = p / M_PAIRS;
    int o = omap[p];
    int slot = atomicAdd(&cursor[(o >> 6) * K_VOL + k], 1);
    sorted_arr[slot] = (imap[p] & 0x3FFFF) | ((o & 63) << 18);
}

// ---------------- main: pull per output tile, LDS fp32 accumulation, NO global atomics ----------------
__launch_bounds__(256, 4)
__global__ void spconv_pull_kernel(const ushort* __restrict__ feats,   // [N_IN][64] f16
                                   const ushort* __restrict__ wt,      // [K][o][c] f16
                                   const int* __restrict__ offsets,    // [NBUCKETS+1]
                                   const int* __restrict__ sorted_arr, // [NPAIRS]
                                   const float* __restrict__ bias,
                                   float* __restrict__ out) {
    __shared__ ushort Asm[64 * LDS_PAD];        // gathered input rows (f16)
    __shared__ ushort Wsm[64 * LDS_PAD];        // W_k [o][c] (f16)
    __shared__ float  out_t[65 * OT_PAD];       // 64 real rows + 1 dummy, fp32
    __shared__ int    olist[64];

    const int otile = blockIdx.x;
    const int tid   = threadIdx.x;
    const int base  = otile * K_VOL;

    // zero the accumulator tile
    for (int i = tid; i < 65 * OT_PAD; i += 256) out_t[i] = 0.f;

    const int wave = tid >> 6;       // = ct (column tile 0..3)
    const int lane = tid & 63;
    const int quad = lane >> 4;
    const int l16  = lane & 15;

    for (int k = 0; k < K_VOL; ++k) {
        int beg = offsets[base + k];
        int end = offsets[base + k + 1];
        if (beg == end) continue;

        __syncthreads();   // protect Wsm (and first time: finish zeroing)
        // stage W_k : 64 rows (o) x 64 (c) f16
        #pragma unroll
        for (int p = 0; p < 2; ++p) {
            int cid = tid + p * 256;
            int row = cid >> 3;
            int ch  = cid & 7;
            *(shortx8*)&Wsm[row * LDS_PAD + ch * 8] =
                *(const shortx8*)&wt[(k << 12) + row * 64 + ch * 8];
        }
        __syncthreads();

        // B fragments for this wave's column tile (held in regs across the run)
        const halfx8 b0 = *(const halfx8*)&Wsm[(wave * 16 + l16) * LDS_PAD + quad * 8];
        const halfx8 b1 = *(const halfx8*)&Wsm[(wave * 16 + l16) * LDS_PAD + 32 + quad * 8];

        for (int pos = beg; pos < end; pos += 64) {
            int g = end - pos; if (g > 64) g = 64;

            __syncthreads();   // protect Asm from previous group's readers
            #pragma unroll
            for (int p = 0; p < 2; ++p) {
                int cid = tid + p * 256;
                int row = cid >> 3;
                int ch  = cid & 7;
                shortx8 v = {0, 0, 0, 0, 0, 0, 0, 0};
                if (row < g) {
                    int rec = sorted_arr[pos + row];
                    int in_row = rec & 0x3FFFF;
                    v = *(const shortx8*)&feats[((size_t)in_row << 6) + ch * 8];
                }
                *(shortx8*)&Asm[row * LDS_PAD + ch * 8] = v;
            }
            if (tid < 64)
                olist[tid] = (tid < g) ? ((sorted_arr[pos + tid] >> 18) & 63) : 64;
            __syncthreads();

            int nsc = (g + 15) >> 4;
            for (int sc = 0; sc < nsc; ++sc) {
                const halfx8 a0 = *(const halfx8*)&Asm[(sc * 16 + l16) * LDS_PAD + quad * 8];
                const halfx8 a1 = *(const halfx8*)&Asm[(sc * 16 + l16) * LDS_PAD + 32 + quad * 8];
                floatx4 acc = {0.f, 0.f, 0.f, 0.f};
                acc = __builtin_amdgcn_mfma_f32_16x16x32_f16(a0, b0, acc, 0, 0, 0);
                acc = __builtin_amdgcn_mfma_f32_16x16x32_f16(a1, b1, acc, 0, 0, 0);
                const int col = wave * 16 + l16;
                const int rb  = sc * 16 + quad * 4;
                #pragma unroll
                for (int r = 0; r < 4; ++r) {
                    int ol = olist[rb + r];
                    atomicAdd(&out_t[ol * OT_PAD + col], acc[r]);   // ds_add_f32
                }
            }
        }
    }

    __syncthreads();
    // epilogue: out[otile*64 + row][*] = out_t[row][*] + bias  (contiguous streaming store)
    #pragma unroll
    for (int p = 0; p < 4; ++p) {
        int cid = tid + p * 256;      // 0..1023
        int row = cid >> 4;           // 0..63
        int ch  = cid & 15;           // float4 chunk
        float4 v = *(float4*)&out_t[row * OT_PAD + ch * 4];
        float4 b = ((const float4*)bias)[ch];
        v.x += b.x; v.y += b.y; v.z += b.z; v.w += b.w;
        ((float4*)out)[(size_t)(otile * 64 + row) * 16 + ch] = v;
    }
}

// ---------------- fallback (round-1 style push, f16 MFMA + fp32 atomics) ----------------
__global__ void init_bias_kernel(const float* __restrict__ bias, float* __restrict__ out, int n4) {
    int i = blockIdx.x * blockDim.x + threadIdx.x;
    if (i >= n4) return;
    int c = (i * 4) & 63;
    float4 b = *(const float4*)(bias + c);
    ((float4*)out)[i] = b;
}

__launch_bounds__(256, 4)
__global__ void spconv_push_f32_kernel(const ushort* __restrict__ feats,
                                       const ushort* __restrict__ wt,
                                       const int* __restrict__ imap,
                                       const int* __restrict__ omap,
                                       float* __restrict__ out) {
    __shared__ ushort Asm[64 * LDS_PAD];
    __shared__ ushort Wsm[64 * LDS_PAD];
    __shared__ int omap_s[64];

    const int k   = blockIdx.y;
    const int m0  = blockIdx.x * 64;
    const int tid = threadIdx.x;
    const int kM  = k * M_PAIRS;

    #pragma unroll
    for (int p = 0; p < 2; ++p) {
        int cid = tid + p * 256;
        int row = cid >> 3;
        int ch  = cid & 7;
        *(shortx8*)&Wsm[row * LDS_PAD + ch * 8] =
            *(const shortx8*)&wt[(k << 12) + row * 64 + ch * 8];
    }
    #pragma unroll
    for (int p = 0; p < 2; ++p) {
        int cid = tid + p * 256;
        int row = cid >> 3;
        int ch  = cid & 7;
        int m   = m0 + row;
        shortx8 v = {0, 0, 0, 0, 0, 0, 0, 0};
        if (m < M_PAIRS) {
            int g = imap[kM + m];
            v = *(const shortx8*)&feats[(g << 6) + ch * 8];
        }
        *(shortx8*)&Asm[row * LDS_PAD + ch * 8] = v;
    }
    if (tid < 64) {
        int m = m0 + tid;
        omap_s[tid] = (m < M_PAIRS) ? omap[kM + m] : -1;
    }
    __syncthreads();

    const int wave = tid >> 6;
    const int lane = tid & 63;
    const int quad = lane >> 4;
    const int l16  = lane & 15;
    const int rbase = wave * 16;

    const halfx8 a0 = *(const halfx8*)&Asm[(rbase + l16) * LDS_PAD + quad * 8];
    const halfx8 a1 = *(const halfx8*)&Asm[(rbase + l16) * LDS_PAD + 32 + quad * 8];

    #pragma unroll
    for (int ct = 0; ct < 4; ++ct) {
        const halfx8 b0 = *(const halfx8*)&Wsm[(ct * 16 + l16) * LDS_PAD + quad * 8];
        const halfx8 b1 = *(const halfx8*)&Wsm[(ct * 16 + l16) * LDS_PAD + 32 + quad * 8];
        floatx4 acc = {0.f, 0.f, 0.f, 0.f};
        acc = __builtin_amdgcn_mfma_f32_16x16x32_f16(a0, b0, acc, 0, 0, 0);
        acc = __builtin_amdgcn_mfma_f32_16x16x32_f16(a1, b1, acc, 0, 0, 0);
        const int col = ct * 16 + l16;
        #pragma unroll
        for (int r = 0; r < 4; ++r) {
            int rl = rbase + quad * 4 + r;
            int orow = omap_s[rl];
            if (orow >= 0) atomicAdd(&out[(orow << 6) + col], acc[r]);
        }
    }
}

extern "C" void kernel_launch(void* const* d_in, const int* in_sizes, int n_in,
                              void* d_out, int out_size, void* d_ws, size_t ws_size,
                              hipStream_t stream) {
    const float* in_feats = (const float*)d_in[0];
    const float* kernelw  = (const float*)d_in[1];
    const float* bias     = (const float*)d_in[2];
    const int*   imap     = (const int*)d_in[3];
    const int*   omap     = (const int*)d_in[4];
    float* out = (float*)d_out;

    char* ws = (char*)d_ws;
    ushort* feats_h = (ushort*)(ws + FEATS_OFF);
    ushort* wt_h    = (ushort*)(ws + WT_OFF);

    int n4 = N_IN * C_IN / 4;
    cvt_feats_kernel<<<(n4 + 255) / 256, 256, 0, stream>>>(in_feats, feats_h, n4);
    cvt_wt_kernel<<<(K_VOL * C_IN * C_OUT + 255) / 256, 256, 0, stream>>>(kernelw, wt_h);

    if (ws_size >= WS_NEEDED) {
        int* offsets = (int*)(ws + OFFS_OFF);
        int* counts  = (int*)(ws + CNT_OFF);
        int* bsum    = (int*)(ws + BSUM_OFF);
        int* sorted_arr = (int*)(ws + SORT_OFF);

        hipMemsetAsync(counts, 0, NBUCKETS * sizeof(int), stream);
        hist_kernel<<<(NPAIRS + 255) / 256, 256, 0, stream>>>(omap, counts);
        scan1_kernel<<<SCAN_NB1, 256, 0, stream>>>(counts, bsum);
        scan2_kernel<<<1, 512, 0, stream>>>(bsum);
        scan3_kernel<<<SCAN_NB1, 256, 0, stream>>>(counts, bsum, offsets);
        fill_kernel<<<(NPAIRS + 255) / 256, 256, 0, stream>>>(imap, omap, counts, sorted_arr);

        spconv_pull_kernel<<<NTILES, 256, 0, stream>>>(feats_h, wt_h, offsets, sorted_arr, bias, out);
    } else {
        int o4 = N_OUT * C_OUT / 4;
        init_bias_kernel<<<(o4 + 255) / 256, 256, 0, stream>>>(bias, out, o4);
        dim3 grid((M_PAIRS + 63) / 64, K_VOL);
        spconv_push_f32_kernel<<<grid, 256, 0, stream>>>(feats_h, wt_h, imap, omap, out);
    }
}

// Round 5
// 1535.934 us; speedup vs baseline: 1.0680x; 1.0680x over previous
//
#include <hip/hip_runtime.h>
#include <hip/hip_fp16.h>

#define N_IN 200000
#define N_OUT 200000
#define K_VOL 27
#define M_PAIRS 100000
#define C_IN 64
#define C_OUT 64
#define NPAIRS (K_VOL * M_PAIRS)     // 2,700,000

#define NTILES (N_OUT / 64)          // 3125 output tiles of 64 rows
#define NBUCKETS (NTILES * K_VOL)    // 84,375
#define SCAN_NB1 330                 // ceil((NBUCKETS+1)/256)

#define LDS_PAD 72                   // ushort row stride for fallback tiles
#define OT_PAD 68                    // float row stride for out_tile (272B)

typedef __attribute__((ext_vector_type(4))) float floatx4;
typedef __attribute__((ext_vector_type(8))) short shortx8;
typedef __attribute__((ext_vector_type(8))) _Float16 halfx8;

// ---- workspace layout (bytes) ----
#define FEATS_OFF   0UL
#define FEATS_BYTES (200000UL * 64 * 2)              // 25,600,000 (f16)
#define WT_OFF      (FEATS_OFF + FEATS_BYTES)
#define WT_BYTES    (27UL * 64 * 64 * 2)             // 221,184 (f16, [k][o][c])
#define OFFS_OFF    ((WT_OFF + WT_BYTES + 255UL) & ~255UL)
#define OFFS_BYTES  (337920UL)                       // (NBUCKETS+1) ints, padded
#define CNT_OFF     (OFFS_OFF + OFFS_BYTES)          // counts, reused as cursor
#define CNT_BYTES   (337920UL)
#define BSUM_OFF    (CNT_OFF + CNT_BYTES)
#define BSUM_BYTES  (2048UL)
#define SORT_OFF    (BSUM_OFF + BSUM_BYTES)
#define SORT_BYTES  (2700000UL * 4)                  // 10,800,000
#define WS_NEEDED   (SORT_OFF + SORT_BYTES)          // ~37.3 MB (proven available in R4)

static __device__ __forceinline__ ushort f32_to_f16_bits(float f) {
    union { _Float16 h; ushort u; } cv;
    cv.h = (_Float16)f;
    return cv.u;
}

// ---------------- prep ----------------
__global__ void cvt_feats_kernel(const float* __restrict__ src, ushort* __restrict__ dst, int n4) {
    int i = blockIdx.x * blockDim.x + threadIdx.x;
    if (i >= n4) return;
    float4 v = ((const float4*)src)[i];
    ushort4 o;
    o.x = f32_to_f16_bits(v.x); o.y = f32_to_f16_bits(v.y);
    o.z = f32_to_f16_bits(v.z); o.w = f32_to_f16_bits(v.w);
    ((ushort4*)dst)[i] = o;
}

// kernel[k][c][o] fp32 -> wt[k][o][c] f16
__global__ void cvt_wt_kernel(const float* __restrict__ w, ushort* __restrict__ wt) {
    int idx = blockIdx.x * blockDim.x + threadIdx.x;
    if (idx >= K_VOL * C_IN * C_OUT) return;
    int k   = idx >> 12;
    int rem = idx & 4095;
    int c   = rem >> 6;
    int o   = rem & 63;
    wt[(k << 12) + (o << 6) + c] = f32_to_f16_bits(w[idx]);
}

// ---------------- counting sort by bucket = (o>>6)*27 + k ----------------
__global__ void hist_kernel(const int* __restrict__ omap, int* __restrict__ counts) {
    int p = blockIdx.x * blockDim.x + threadIdx.x;
    if (p >= NPAIRS) return;
    int k = p / M_PAIRS;
    int o = omap[p];
    atomicAdd(&counts[(o >> 6) * K_VOL + k], 1);
}

__global__ void scan1_kernel(const int* __restrict__ counts, int* __restrict__ bsum) {
    __shared__ int sd[256];
    int tid = threadIdx.x;
    int i = blockIdx.x * 256 + tid;
    sd[tid] = (i < NBUCKETS) ? counts[i] : 0;
    __syncthreads();
    for (int s = 128; s > 0; s >>= 1) {
        if (tid < s) sd[tid] += sd[tid + s];
        __syncthreads();
    }
    if (tid == 0) bsum[blockIdx.x] = sd[0];
}

__global__ void scan2_kernel(int* __restrict__ bsum) {
    __shared__ int sd[512];
    int tid = threadIdx.x;
    int v = (tid < SCAN_NB1) ? bsum[tid] : 0;
    sd[tid] = v;
    __syncthreads();
    for (int off = 1; off < 512; off <<= 1) {
        int t = (tid >= off) ? sd[tid - off] : 0;
        __syncthreads();
        sd[tid] += t;
        __syncthreads();
    }
    if (tid < SCAN_NB1) bsum[tid] = sd[tid] - v;  // exclusive
}

__global__ void scan3_kernel(int* __restrict__ counts_cursor, const int* __restrict__ bsum,
                             int* __restrict__ offsets) {
    __shared__ int sd[256];
    int tid = threadIdx.x;
    int i = blockIdx.x * 256 + tid;
    int v = (i < NBUCKETS) ? counts_cursor[i] : 0;
    sd[tid] = v;
    __syncthreads();
    for (int off = 1; off < 256; off <<= 1) {
        int t = (tid >= off) ? sd[tid - off] : 0;
        __syncthreads();
        sd[tid] += t;
        __syncthreads();
    }
    int excl = sd[tid] - v + bsum[blockIdx.x];
    if (i <= NBUCKETS) offsets[i] = excl;
    if (i < NBUCKETS) counts_cursor[i] = excl;
}

// sorted record: in_row (18b) | o_local (6b) << 18
__global__ void fill_kernel(const int* __restrict__ imap, const int* __restrict__ omap,
                            int* __restrict__ cursor, int* __restrict__ sorted_arr) {
    int p = blockIdx.x * blockDim.x + threadIdx.x;
    if (p >= NPAIRS) return;
    int k = p / M_PAIRS;
    int o = omap[p];
    int slot = atomicAdd(&cursor[(o >> 6) * K_VOL + k], 1);
    sorted_arr[slot] = (imap[p] & 0x3FFFF) | ((o & 63) << 18);
}

// ---------------- main: barrier-free per-wave pull, LDS fp32 merge ----------------
// One block per 64-row output tile. Each wave independently grabs 16-row slabs
// (rotated by k to balance), gathers A straight from global into registers,
// holds all 4 column-tiles' B-frags in regs, merges C via ds_add_f32.
// Only 2 __syncthreads in the whole kernel (after zero, before epilogue).
__launch_bounds__(256, 6)
__global__ void spconv_pull2_kernel(const ushort* __restrict__ feats,   // [N_IN][64] f16
                                    const ushort* __restrict__ wt,      // [K][o][c] f16
                                    const int* __restrict__ offsets,    // [NBUCKETS+1]
                                    const int* __restrict__ sorted_arr, // [NPAIRS]
                                    const float* __restrict__ bias,
                                    float* __restrict__ out) {
    __shared__ float out_t[65 * OT_PAD];   // 64 rows + 1 dummy, fp32

    const int otile = blockIdx.x;
    const int tid   = threadIdx.x;
    const int wave  = tid >> 6;
    const int lane  = tid & 63;
    const int quad  = lane >> 4;
    const int l16   = lane & 15;
    const int base  = otile * K_VOL;

    for (int i = tid; i < 65 * OT_PAD; i += 256) out_t[i] = 0.f;
    __syncthreads();

    for (int k = 0; k < K_VOL; ++k) {
        int beg = offsets[base + k];
        int end = offsets[base + k + 1];
        int n = end - beg;
        if (n <= 0) continue;
        int nslabs = (n + 15) >> 4;
        int s0 = (wave + k) & 3;        // rotate slab ownership across k for balance
        if (s0 >= nslabs) continue;

        // B fragments, all 4 column tiles: B[k=quad*8+j][n=ct*16+l16] from wt[o][c]
        halfx8 b0[4], b1[4];
        #pragma unroll
        for (int ct = 0; ct < 4; ++ct) {
            const ushort* wp = &wt[(k << 12) + (ct * 16 + l16) * 64 + quad * 8];
            b0[ct] = *(const halfx8*)wp;
            b1[ct] = *(const halfx8*)(wp + 32);
        }

        for (int s = s0; s < nslabs; s += 4) {
            int p = beg + s * 16;
            int g = end - p; if (g > 16) g = 16;

            int rec = (l16 < g) ? sorted_arr[p + l16] : (64 << 18);  // dummy row 64
            halfx8 a0 = {0, 0, 0, 0, 0, 0, 0, 0};
            halfx8 a1 = {0, 0, 0, 0, 0, 0, 0, 0};
            if (l16 < g) {
                const ushort* fp = &feats[((size_t)(rec & 0x3FFFF) << 6) + quad * 8];
                a0 = *(const halfx8*)fp;        // A[m=l16][k=quad*8..]
                a1 = *(const halfx8*)(fp + 32); // A[m=l16][k=quad*8+32..]
            }
            // my quad's 4 target rows (C row = quad*4 + r)
            int ol[4];
            #pragma unroll
            for (int r = 0; r < 4; ++r)
                ol[r] = (__shfl(rec, quad * 4 + r, 16) >> 18) & 63;

            #pragma unroll
            for (int ct = 0; ct < 4; ++ct) {
                floatx4 acc = {0.f, 0.f, 0.f, 0.f};
                acc = __builtin_amdgcn_mfma_f32_16x16x32_f16(a0, b0[ct], acc, 0, 0, 0);
                acc = __builtin_amdgcn_mfma_f32_16x16x32_f16(a1, b1[ct], acc, 0, 0, 0);
                const int col = ct * 16 + l16;
                #pragma unroll
                for (int r = 0; r < 4; ++r)
                    atomicAdd(&out_t[ol[r] * OT_PAD + col], acc[r]);   // ds_add_f32
            }
        }
    }

    __syncthreads();
    // epilogue: contiguous streaming store + bias
    #pragma unroll
    for (int p = 0; p < 4; ++p) {
        int cid = tid + p * 256;      // 0..1023
        int row = cid >> 4;           // 0..63
        int ch  = cid & 15;
        float4 v = *(float4*)&out_t[row * OT_PAD + ch * 4];
        float4 b = ((const float4*)bias)[ch];
        v.x += b.x; v.y += b.y; v.z += b.z; v.w += b.w;
        ((float4*)out)[(size_t)(otile * 64 + row) * 16 + ch] = v;
    }
}

// ---------------- fallback (round-1 style push, f16 MFMA + fp32 atomics) ----------------
__global__ void init_bias_kernel(const float* __restrict__ bias, float* __restrict__ out, int n4) {
    int i = blockIdx.x * blockDim.x + threadIdx.x;
    if (i >= n4) return;
    int c = (i * 4) & 63;
    float4 b = *(const float4*)(bias + c);
    ((float4*)out)[i] = b;
}

__launch_bounds__(256, 4)
__global__ void spconv_push_f32_kernel(const ushort* __restrict__ feats,
                                       const ushort* __restrict__ wt,
                                       const int* __restrict__ imap,
                                       const int* __restrict__ omap,
                                       float* __restrict__ out) {
    __shared__ ushort Asm[64 * LDS_PAD];
    __shared__ ushort Wsm[64 * LDS_PAD];
    __shared__ int omap_s[64];

    const int k   = blockIdx.y;
    const int m0  = blockIdx.x * 64;
    const int tid = threadIdx.x;
    const int kM  = k * M_PAIRS;

    #pragma unroll
    for (int p = 0; p < 2; ++p) {
        int cid = tid + p * 256;
        int row = cid >> 3;
        int ch  = cid & 7;
        *(shortx8*)&Wsm[row * LDS_PAD + ch * 8] =
            *(const shortx8*)&wt[(k << 12) + row * 64 + ch * 8];
    }
    #pragma unroll
    for (int p = 0; p < 2; ++p) {
        int cid = tid + p * 256;
        int row = cid >> 3;
        int ch  = cid & 7;
        int m   = m0 + row;
        shortx8 v = {0, 0, 0, 0, 0, 0, 0, 0};
        if (m < M_PAIRS) {
            int g = imap[kM + m];
            v = *(const shortx8*)&feats[(g << 6) + ch * 8];
        }
        *(shortx8*)&Asm[row * LDS_PAD + ch * 8] = v;
    }
    if (tid < 64) {
        int m = m0 + tid;
        omap_s[tid] = (m < M_PAIRS) ? omap[kM + m] : -1;
    }
    __syncthreads();

    const int wave = tid >> 6;
    const int lane = tid & 63;
    const int quad = lane >> 4;
    const int l16  = lane & 15;
    const int rbase = wave * 16;

    const halfx8 a0 = *(const halfx8*)&Asm[(rbase + l16) * LDS_PAD + quad * 8];
    const halfx8 a1 = *(const halfx8*)&Asm[(rbase + l16) * LDS_PAD + 32 + quad * 8];

    #pragma unroll
    for (int ct = 0; ct < 4; ++ct) {
        const halfx8 b0 = *(const halfx8*)&Wsm[(ct * 16 + l16) * LDS_PAD + quad * 8];
        const halfx8 b1 = *(const halfx8*)&Wsm[(ct * 16 + l16) * LDS_PAD + 32 + quad * 8];
        floatx4 acc = {0.f, 0.f, 0.f, 0.f};
        acc = __builtin_amdgcn_mfma_f32_16x16x32_f16(a0, b0, acc, 0, 0, 0);
        acc = __builtin_amdgcn_mfma_f32_16x16x32_f16(a1, b1, acc, 0, 0, 0);
        const int col = ct * 16 + l16;
        #pragma unroll
        for (int r = 0; r < 4; ++r) {
            int rl = rbase + quad * 4 + r;
            int orow = omap_s[rl];
            if (orow >= 0) atomicAdd(&out[(orow << 6) + col], acc[r]);
        }
    }
}

extern "C" void kernel_launch(void* const* d_in, const int* in_sizes, int n_in,
                              void* d_out, int out_size, void* d_ws, size_t ws_size,
                              hipStream_t stream) {
    const float* in_feats = (const float*)d_in[0];
    const float* kernelw  = (const float*)d_in[1];
    const float* bias     = (const float*)d_in[2];
    const int*   imap     = (const int*)d_in[3];
    const int*   omap     = (const int*)d_in[4];
    float* out = (float*)d_out;

    char* ws = (char*)d_ws;
    ushort* feats_h = (ushort*)(ws + FEATS_OFF);
    ushort* wt_h    = (ushort*)(ws + WT_OFF);

    int n4 = N_IN * C_IN / 4;
    cvt_feats_kernel<<<(n4 + 255) / 256, 256, 0, stream>>>(in_feats, feats_h, n4);
    cvt_wt_kernel<<<(K_VOL * C_IN * C_OUT + 255) / 256, 256, 0, stream>>>(kernelw, wt_h);

    if (ws_size >= WS_NEEDED) {
        int* offsets = (int*)(ws + OFFS_OFF);
        int* counts  = (int*)(ws + CNT_OFF);
        int* bsum    = (int*)(ws + BSUM_OFF);
        int* sorted_arr = (int*)(ws + SORT_OFF);

        hipMemsetAsync(counts, 0, NBUCKETS * sizeof(int), stream);
        hist_kernel<<<(NPAIRS + 255) / 256, 256, 0, stream>>>(omap, counts);
        scan1_kernel<<<SCAN_NB1, 256, 0, stream>>>(counts, bsum);
        scan2_kernel<<<1, 512, 0, stream>>>(bsum);
        scan3_kernel<<<SCAN_NB1, 256, 0, stream>>>(counts, bsum, offsets);
        fill_kernel<<<(NPAIRS + 255) / 256, 256, 0, stream>>>(imap, omap, counts, sorted_arr);

        spconv_pull2_kernel<<<NTILES, 256, 0, stream>>>(feats_h, wt_h, offsets, sorted_arr, bias, out);
    } else {
        int o4 = N_OUT * C_OUT / 4;
        init_bias_kernel<<<(o4 + 255) / 256, 256, 0, stream>>>(bias, out, o4);
        dim3 grid((M_PAIRS + 63) / 64, K_VOL);
        spconv_push_f32_kernel<<<grid, 256, 0, stream>>>(feats_h, wt_h, imap, omap, out);
    }
}